// Round 2
// baseline (599.904 us; speedup 1.0000x reference)
//
#include <hip/hip_runtime.h>
#include <hip/hip_bf16.h>
#include <hip/hip_cooperative_groups.h>

namespace cg = cooperative_groups;

#define L_LAYERS 4
#define B_DIM 256
#define H_DIM 65536
#define KC 1024                    // K-chunk per block -> 64 splits per layer
#define BK 64                      // K per staging step (2 MFMA k-steps)
#define NKT (KC / BK)              // 16
#define NKZ (H_DIM / KC)           // 64
#define NSLICE (L_LAYERS * NKZ)    // 256 partial-Gram slices == 256 blocks (1/CU, co-resident)
#define LDSTR 72                   // shorts per LDS row (144 B: 16B-aligned, 2-way-max bank class)

using bf16x8_t = __attribute__((ext_vector_type(8))) short;   // MFMA A/B operand (4 VGPRs)
using shortx8  = __attribute__((ext_vector_type(8))) short;   // 16-byte LDS store
using shortx4  = __attribute__((ext_vector_type(4))) short;   // 8-byte global store
using floatx4  = __attribute__((ext_vector_type(4))) float;   // MFMA accumulator

__device__ __forceinline__ unsigned short f2bf(float f) {
    // round-to-nearest-even fp32 -> bf16 (finite inputs)
    unsigned u = __float_as_uint(f);
    return (unsigned short)((u + 0x7fffu + ((u >> 16) & 1u)) >> 16);
}

// ONE cooperative kernel, 256 blocks x 512 threads (1 block/CU, all co-resident):
//   phase 1: per-(layer,kz) partial Gram -> bf16 slice S[bx] (input read EXACTLY once)
//   grid.sync
//   phase 2: each block reduces 4 G-rows (kept in LDS), writes only the 4x256 diagonal
//   grid.sync
//   phase 3: loss math on the retained rows + hot diagonal, one atomicAdd per row
__global__ __launch_bounds__(512, 2) void fused_kernel(const float* __restrict__ hs,
                                                       const int* __restrict__ task,
                                                       float* __restrict__ out,
                                                       short* __restrict__ S,
                                                       float* __restrict__ diag) {
    __shared__ short lds[B_DIM * LDSTR];   // 36 KB gram staging; overlaid in phases 2/3
    __shared__ float sa[8], sb[8];
    __shared__ int s_odd_nz;

    cg::grid_group grid = cg::this_grid();

    const int tid = threadIdx.x;
    const int bx  = blockIdx.x;            // 0..255
    const int l   = bx >> 6;
    const int kz  = bx & (NKZ - 1);

    // ---------------- phase 1: partial Gram (identical to verified R1 gram) ----------------
    {
        const int wave = tid >> 6, lane = tid & 63;
        const int wm = wave >> 1;              // 0..3: 64-row strip
        const int wn = wave & 1;               // 0..1: 128-col strip
        const int mrow = lane & 15, quad = lane >> 4;

        const int r = tid >> 1;
        const int h = tid & 1;
        const float* gp = hs + ((size_t)l * B_DIM + r) * H_DIM + (size_t)kz * KC + h * 32;
        const int ldsw = r * LDSTR + h * 32;   // short units

        floatx4 acc[4][8];
#pragma unroll
        for (int i = 0; i < 4; ++i)
#pragma unroll
            for (int j = 0; j < 8; ++j) acc[i][j] = (floatx4)0.0f;

        float4 pv[8];
#pragma unroll
        for (int q = 0; q < 8; ++q) pv[q] = *(const float4*)(gp + q * 4);

        for (int kt = 0; kt < NKT; ++kt) {
#pragma unroll
            for (int q = 0; q < 4; ++q) {
                shortx8 w;
                w[0] = (short)f2bf(pv[2 * q].x);     w[1] = (short)f2bf(pv[2 * q].y);
                w[2] = (short)f2bf(pv[2 * q].z);     w[3] = (short)f2bf(pv[2 * q].w);
                w[4] = (short)f2bf(pv[2 * q + 1].x); w[5] = (short)f2bf(pv[2 * q + 1].y);
                w[6] = (short)f2bf(pv[2 * q + 1].z); w[7] = (short)f2bf(pv[2 * q + 1].w);
                *(shortx8*)&lds[ldsw + q * 8] = w;   // prior iteration's trailing barrier protects this
            }
            if (kt < NKT - 1) {
                const float* gn = gp + (kt + 1) * BK;
#pragma unroll
                for (int q = 0; q < 8; ++q) pv[q] = *(const float4*)(gn + q * 4);
            }
            __syncthreads();

#pragma unroll
            for (int kk = 0; kk < 2; ++kk) {
                bf16x8_t af[4], bfv[8];
#pragma unroll
                for (int i = 0; i < 4; ++i)
                    af[i] = *(const bf16x8_t*)&lds[(wm * 64 + i * 16 + mrow) * LDSTR + kk * 32 + quad * 8];
#pragma unroll
                for (int j = 0; j < 8; ++j)
                    bfv[j] = *(const bf16x8_t*)&lds[(wn * 128 + j * 16 + mrow) * LDSTR + kk * 32 + quad * 8];
#pragma unroll
                for (int i = 0; i < 4; ++i)
#pragma unroll
                    for (int j = 0; j < 8; ++j)
                        acc[i][j] = __builtin_amdgcn_mfma_f32_16x16x32_bf16(af[i], bfv[j], acc[i][j], 0, 0, 0);
            }
            __syncthreads();
        }

        // store partial Gram (bf16, transposed == identical by symmetry) -> 8 B vector stores
        short* Ssl = S + (size_t)bx * (B_DIM * B_DIM);
#pragma unroll
        for (int i = 0; i < 4; ++i) {
            const int row0 = wm * 64 + i * 16 + quad * 4;
#pragma unroll
            for (int j = 0; j < 8; ++j) {
                const int col = wn * 128 + j * 16 + mrow;
                shortx4 v;
                v[0] = (short)f2bf(acc[i][j][0]);
                v[1] = (short)f2bf(acc[i][j][1]);
                v[2] = (short)f2bf(acc[i][j][2]);
                v[3] = (short)f2bf(acc[i][j][3]);
                *(shortx4*)&Ssl[(size_t)col * B_DIM + row0] = v;
            }
        }
    }

    __threadfence();       // make S visible across XCD L2s before any block reads it
    grid.sync();

    // ---------------- phase 2: reduce 4 G-rows per block, keep them in LDS ----------------
    float*  rowsL = (float*)lds;                 // [4][256] floats = 4 KB (survives into phase 3)
    float2* red   = (float2*)(lds + 2048);       // [4][128] float2 = 4 KB scratch (byte offset 4096)

    const int z  = tid >> 7;                     // 0..3: kz quarter
    const int j2 = tid & 127;                    // column pair
    {
#pragma unroll 1
        for (int q = 0; q < 4; ++q) {
            const int job = bx * 4 + q;          // (l,i) row job, 0..1023
            const int jl  = job >> 8;
            const int ji  = job & 255;
            const unsigned* bp = (const unsigned*)S
                + (size_t)(jl * NKZ + z * 16) * (B_DIM * B_DIM / 2)
                + ji * (B_DIM / 2) + j2;
            float s0 = 0.0f, s1 = 0.0f;
#pragma unroll
            for (int t = 0; t < 16; ++t) {
                const unsigned u = bp[(size_t)t * (B_DIM * B_DIM / 2)];
                s0 += __uint_as_float(u << 16);             // low bf16
                s1 += __uint_as_float(u & 0xffff0000u);     // high bf16
            }
            red[z * 128 + j2] = float2{s0, s1};
            __syncthreads();
            if (z == 0) {
                const float2 p0 = red[j2], p1 = red[128 + j2], p2 = red[256 + j2], p3 = red[384 + j2];
                const float g0 = p0.x + p1.x + p2.x + p3.x;
                const float g1 = p0.y + p1.y + p2.y + p3.y;
                rowsL[q * 256 + 2 * j2]     = g0;
                rowsL[q * 256 + 2 * j2 + 1] = g1;
                if (2 * j2 == ji)     diag[jl * 256 + ji] = g0;   // this row's diagonal element
                if (2 * j2 + 1 == ji) diag[jl * 256 + ji] = g1;
            }
            __syncthreads();
        }
    }

    __threadfence();       // diag visible across XCDs
    grid.sync();

    // ---------------- phase 3: loss from retained rows + hot 4 KB diagonal ----------------
    // block-uniform int64-vs-int32 detection for task_type (proven in prior session)
    if (tid == 0) s_odd_nz = 0;
    __syncthreads();
    if (tid < 128 && task[2 * tid + 1] != 0) s_odd_nz = 1;
    __syncthreads();
    const bool is64 = (s_odd_nz == 0);

#pragma unroll 1
    for (int q = 0; q < 4; ++q) {
        const int job = bx * 4 + q;
        const int jl  = job >> 8;
        const int ji  = job & 255;
        float a = 0.0f, b = 0.0f;
        if (tid < 256) {
            const int j   = tid;
            const float gij = rowsL[q * 256 + j];
            const float gii = diag[jl * 256 + ji];
            const float gjj = diag[jl * 256 + j];
            const float nd  = gij * rsqrtf(gii) * rsqrtf(gjj);
            const float d2  = fmaxf(2.0f - 2.0f * nd, 0.0f);
            const float w   = __expf(-2.0f * d2);   // exp(-d2 / 0.5)
            const int ti = is64 ? task[2 * ji] : task[ji];
            const int tj = is64 ? task[2 * j]  : task[j];
            const float pm = (ti == tj && ji != j) ? 1.0f : 0.0f;
            a = w * pm; b = w;
        }
#pragma unroll
        for (int off = 32; off > 0; off >>= 1) {
            a += __shfl_down(a, off);
            b += __shfl_down(b, off);
        }
        const int wv = tid >> 6, ln = tid & 63;
        if (ln == 0) { sa[wv] = a; sb[wv] = b; }
        __syncthreads();
        if (tid == 0) {
            const float A  = sa[0] + sa[1] + sa[2] + sa[3] + sa[4] + sa[5] + sa[6] + sa[7];
            const float Bb = sb[0] + sb[1] + sb[2] + sb[3] + sb[4] + sb[5] + sb[6] + sb[7];
            atomicAdd(out, -logf((A + 1e-8f) / (Bb + 1e-8f)) * (0.2f / 1024.0f));
        }
        __syncthreads();
    }
}

extern "C" void kernel_launch(void* const* d_in, const int* in_sizes, int n_in,
                              void* d_out, int out_size, void* d_ws, size_t ws_size,
                              hipStream_t stream) {
    const float* hs   = (const float*)d_in[0];
    const int*   task = (const int*)d_in[1];
    float*       out  = (float*)d_out;

    short* S    = (short*)d_ws;                                   // 256 slices x 128 KB = 32 MB (bf16)
    float* diag = (float*)(S + (size_t)NSLICE * (B_DIM * B_DIM)); // + 4 KB

    hipMemsetAsync(out, 0, sizeof(float), stream);

    void* args[] = { (void*)&hs, (void*)&task, (void*)&out, (void*)&S, (void*)&diag };
    hipLaunchCooperativeKernel(fused_kernel, dim3(NSLICE), dim3(512), args, 0, stream);
}

// Round 5
// 430.356 us; speedup vs baseline: 1.3940x; 1.3940x over previous
//
#include <hip/hip_runtime.h>
#include <hip/hip_bf16.h>

#define L_LAYERS 4
#define B_DIM 256
#define H_DIM 65536
#define KC 1024                    // K-chunk per block -> 64 splits per layer
#define BK 64                      // K per staging step (2 MFMA k-steps)
#define NKT (KC / BK)              // 16
#define NKZ (H_DIM / KC)           // 64
#define NSLICE (L_LAYERS * NKZ)    // 256 partial-Gram slices
#define LDSTR 72                   // shorts per LDS row (144 B: 16B-aligned, 2-way-max bank class)

using bf16x8_t = __attribute__((ext_vector_type(8))) short;   // MFMA A/B operand (4 VGPRs)
using shortx8  = __attribute__((ext_vector_type(8))) short;   // 16-byte LDS store
using shortx4  = __attribute__((ext_vector_type(4))) short;   // 8-byte global store
using floatx4  = __attribute__((ext_vector_type(4))) float;   // MFMA accumulator

__device__ __forceinline__ unsigned short f2bf(float f) {
    // round-to-nearest-even fp32 -> bf16 (finite inputs)
    unsigned u = __float_as_uint(f);
    return (unsigned short)((u + 0x7fffu + ((u >> 16) & 1u)) >> 16);
}

// One block per (layer, kz): reads 256 rows x KC floats EXACTLY ONCE (1x fetch),
// computes the full 256x256 Gram partial, stores it bf16 to its own slice.
// (Byte-identical to the R1 gram that benched successfully; 36 KB LDS, single buffer.)
__global__ __launch_bounds__(512, 2) void gram_kernel(const float* __restrict__ hs,
                                                      short* __restrict__ S) {
    __shared__ short lds[B_DIM * LDSTR];   // 256 x 72 shorts = 36 KB

    const int tid = threadIdx.x;
    const int bx  = blockIdx.x;            // 0..255
    const int l   = bx >> 6;
    const int kz  = bx & (NKZ - 1);

    const int wave = tid >> 6, lane = tid & 63;
    const int wm = wave >> 1;              // 0..3: 64-row strip
    const int wn = wave & 1;               // 0..1: 128-col strip
    const int mrow = lane & 15, quad = lane >> 4;

    // staging: thread t covers row r = t>>1, floats [h*32, h*32+32) of the BK=64 window
    const int r = tid >> 1;
    const int h = tid & 1;
    const float* gp = hs + ((size_t)l * B_DIM + r) * H_DIM + (size_t)kz * KC + h * 32;
    const int ldsw = r * LDSTR + h * 32;   // short units

    floatx4 acc[4][8];
#pragma unroll
    for (int i = 0; i < 4; ++i)
#pragma unroll
        for (int j = 0; j < 8; ++j) acc[i][j] = (floatx4)0.0f;

    // register prefetch of K-slice 0: 128 B contiguous per thread
    float4 pv[8];
#pragma unroll
    for (int q = 0; q < 8; ++q) pv[q] = *(const float4*)(gp + q * 4);

    for (int kt = 0; kt < NKT; ++kt) {
        // convert current slice to bf16 and stage to LDS
#pragma unroll
        for (int q = 0; q < 4; ++q) {
            shortx8 w;
            w[0] = (short)f2bf(pv[2 * q].x);     w[1] = (short)f2bf(pv[2 * q].y);
            w[2] = (short)f2bf(pv[2 * q].z);     w[3] = (short)f2bf(pv[2 * q].w);
            w[4] = (short)f2bf(pv[2 * q + 1].x); w[5] = (short)f2bf(pv[2 * q + 1].y);
            w[6] = (short)f2bf(pv[2 * q + 1].z); w[7] = (short)f2bf(pv[2 * q + 1].w);
            *(shortx8*)&lds[ldsw + q * 8] = w;   // previous iteration's trailing barrier protects this
        }

        // issue next slice's loads; they land during the MFMA phase
        if (kt < NKT - 1) {
            const float* gn = gp + (kt + 1) * BK;
#pragma unroll
            for (int q = 0; q < 8; ++q) pv[q] = *(const float4*)(gn + q * 4);
        }
        __syncthreads();

#pragma unroll
        for (int kk = 0; kk < 2; ++kk) {
            bf16x8_t af[4], bfv[8];
#pragma unroll
            for (int i = 0; i < 4; ++i)
                af[i] = *(const bf16x8_t*)&lds[(wm * 64 + i * 16 + mrow) * LDSTR + kk * 32 + quad * 8];
#pragma unroll
            for (int j = 0; j < 8; ++j)
                bfv[j] = *(const bf16x8_t*)&lds[(wn * 128 + j * 16 + mrow) * LDSTR + kk * 32 + quad * 8];
#pragma unroll
            for (int i = 0; i < 4; ++i)
#pragma unroll
                for (int j = 0; j < 8; ++j)
                    acc[i][j] = __builtin_amdgcn_mfma_f32_16x16x32_bf16(af[i], bfv[j], acc[i][j], 0, 0, 0);
        }
        __syncthreads();
    }

    // store partial Gram (bf16, transposed == identical by symmetry) -> 8 B vector stores
    short* Ssl = S + (size_t)bx * (B_DIM * B_DIM);
#pragma unroll
    for (int i = 0; i < 4; ++i) {
        const int row0 = wm * 64 + i * 16 + quad * 4;
#pragma unroll
        for (int j = 0; j < 8; ++j) {
            const int col = wn * 128 + j * 16 + mrow;
            shortx4 v;
            v[0] = (short)f2bf(acc[i][j][0]);
            v[1] = (short)f2bf(acc[i][j][1]);
            v[2] = (short)f2bf(acc[i][j][2]);
            v[3] = (short)f2bf(acc[i][j][3]);
            *(shortx4*)&Ssl[(size_t)col * B_DIM + row0] = v;
        }
    }
}

// diag[l][i] = sum over kz of S[(l,kz)][i][i] — tiny (4 blocks x 256 threads)
__global__ __launch_bounds__(256) void diag_kernel(const short* __restrict__ S,
                                                   float* __restrict__ diag) {
    const int l = blockIdx.x, i = threadIdx.x;
    const unsigned short* p = (const unsigned short*)S
        + (size_t)l * NKZ * (B_DIM * B_DIM) + (size_t)i * (B_DIM + 1);
    float s = 0.0f;
#pragma unroll
    for (int kz = 0; kz < NKZ; ++kz)
        s += __uint_as_float((unsigned)p[(size_t)kz * (B_DIM * B_DIM)] << 16);
    diag[l * B_DIM + i] = s;
}

// One block per (l,i): reduce G-row i across the 64 kz slices (column-pair per
// thread via one uint load), then apply the loss math inline. G is never stored.
__global__ __launch_bounds__(128) void reduceloss_kernel(const short* __restrict__ S,
                                                         const float* __restrict__ diag,
                                                         const int* __restrict__ task,
                                                         float* __restrict__ out) {
    const int li = blockIdx.x;             // l*256 + i
    const int j2 = threadIdx.x;            // 0..127: column pair
    const int l  = li >> 8;
    const int i  = li & 255;

    // block-uniform int64-vs-int32 detection for task_type (proven pattern)
    __shared__ int s_odd_nz;
    __shared__ float sa[2], sb[2];
    if (j2 == 0) s_odd_nz = 0;
    __syncthreads();
    if (task[2 * j2 + 1] != 0) s_odd_nz = 1;
    __syncthreads();
    const bool is64 = (s_odd_nz == 0);

    const unsigned* bp = (const unsigned*)S
        + (size_t)l * NKZ * (B_DIM * B_DIM / 2) + i * (B_DIM / 2) + j2;
    float s0 = 0.0f, s1 = 0.0f;
#pragma unroll
    for (int kz = 0; kz < NKZ; ++kz) {
        const unsigned u = bp[(size_t)kz * (B_DIM * B_DIM / 2)];
        s0 += __uint_as_float(u << 16);             // low bf16
        s1 += __uint_as_float(u & 0xffff0000u);     // high bf16
    }

    const int j0 = 2 * j2, j1 = 2 * j2 + 1;
    const float rgii = rsqrtf(diag[l * B_DIM + i]);
    const float nd0  = s0 * rgii * rsqrtf(diag[l * B_DIM + j0]);
    const float nd1  = s1 * rgii * rsqrtf(diag[l * B_DIM + j1]);
    const float w0   = __expf(-2.0f * fmaxf(2.0f - 2.0f * nd0, 0.0f));  // exp(-d2/0.5)
    const float w1   = __expf(-2.0f * fmaxf(2.0f - 2.0f * nd1, 0.0f));
    const int ti  = is64 ? task[2 * i]  : task[i];
    const int tj0 = is64 ? task[2 * j0] : task[j0];
    const int tj1 = is64 ? task[2 * j1] : task[j1];
    float a = ((ti == tj0 && i != j0) ? w0 : 0.0f) + ((ti == tj1 && i != j1) ? w1 : 0.0f);
    float b = w0 + w1;

#pragma unroll
    for (int off = 32; off > 0; off >>= 1) {
        a += __shfl_down(a, off);
        b += __shfl_down(b, off);
    }
    const int wv = j2 >> 6, ln = j2 & 63;
    if (ln == 0) { sa[wv] = a; sb[wv] = b; }
    __syncthreads();
    if (j2 == 0) {
        const float A  = sa[0] + sa[1];
        const float Bb = sb[0] + sb[1];
        atomicAdd(out, -logf((A + 1e-8f) / (Bb + 1e-8f)) * (0.2f / 1024.0f));
    }
}

extern "C" void kernel_launch(void* const* d_in, const int* in_sizes, int n_in,
                              void* d_out, int out_size, void* d_ws, size_t ws_size,
                              hipStream_t stream) {
    const float* hs   = (const float*)d_in[0];
    const int*   task = (const int*)d_in[1];
    float*       out  = (float*)d_out;

    short* S    = (short*)d_ws;                                   // 256 slices x 128 KB = 32 MB (bf16)
    float* diag = (float*)(S + (size_t)NSLICE * (B_DIM * B_DIM)); // + 4 KB

    hipMemsetAsync(out, 0, sizeof(float), stream);

    gram_kernel<<<dim3(NSLICE), dim3(512), 0, stream>>>(hs, S);
    diag_kernel<<<dim3(L_LAYERS), dim3(256), 0, stream>>>(S, diag);
    reduceloss_kernel<<<dim3(L_LAYERS * B_DIM), dim3(128), 0, stream>>>(S, diag, task, out);
}